// Round 3
// baseline (407.816 us; speedup 1.0000x reference)
//
#include <hip/hip_runtime.h>
#include <math.h>

// Problem constants (reference: B=1, N=64, Q=K=512, C_Q=C_K=C_V=256, H=8, c=32)
#define NSEQ   64
#define QLEN   512
#define KLEN   512
#define CIN    256
#define HEADS  8
#define CH     32
#define HIDDIM 256
#define M_TOTAL (NSEQ * QLEN)   // 32768 rows for all projections
#define L2E    1.4426950408889634f

typedef _Float16 f16x8 __attribute__((ext_vector_type(8)));
typedef _Float16 f16x4 __attribute__((ext_vector_type(4)));
typedef __fp16   fp16x2 __attribute__((ext_vector_type(2)));   // cvt_pkrtz native type
typedef float    f32x4 __attribute__((ext_vector_type(4)));

// Async global->LDS, 16B per lane. Dest must be linear in lane order;
// swizzle is applied on the GLOBAL source and mirrored on the LDS read (G21).
__device__ __forceinline__ void gload16(const void* g, void* l) {
    __builtin_amdgcn_global_load_lds(
        (const __attribute__((address_space(1))) void*)g,
        (__attribute__((address_space(3))) void*)l, 16, 0, 0);
}

// exp2 without the OCML edge-case fixup (args are well within range).
__device__ __forceinline__ float exp2_fast(float x) {
#if __has_builtin(__builtin_amdgcn_exp2f)
    return __builtin_amdgcn_exp2f(x);
#else
    float r; asm("v_exp_f32 %0, %1" : "=v"(r) : "v"(x)); return r;
#endif
}

// ---------------------------------------------------------------------------
// Weight transpose+cast: W[256 in][256 out] fp32 -> WT[256 out][256 in] fp16.
// Slab order: 0=wq, 1=wg, 2=wk, 3=wv, 4=wo.
// ---------------------------------------------------------------------------
__global__ __launch_bounds__(256) void wcast_kernel(
    const float* __restrict__ w0, const float* __restrict__ w1,
    const float* __restrict__ w2, const float* __restrict__ w3,
    const float* __restrict__ w4, _Float16* __restrict__ wt)
{
    __shared__ float t[64][65];
    const float* W;
    switch (blockIdx.z) {
        case 0: W = w0; break; case 1: W = w1; break;
        case 2: W = w2; break; case 3: W = w3; break;
        default: W = w4;
    }
    _Float16* WT = wt + (size_t)blockIdx.z * 65536;
    const int i0 = blockIdx.x * 64, o0 = blockIdx.y * 64;
    const int tid = threadIdx.x;
    const int rr = tid >> 4, c4 = tid & 15;
    #pragma unroll
    for (int i = 0; i < 4; ++i) {
        const int row = rr + i * 16;
        *(float4*)&t[row][c4 * 4] = *(const float4*)&W[(size_t)(i0 + row) * 256 + o0 + c4 * 4];
    }
    __syncthreads();
    #pragma unroll
    for (int i = 0; i < 4; ++i) {
        const int row = rr + i * 16;            // out-dim row
        f16x4 v;
        #pragma unroll
        for (int j = 0; j < 4; ++j) v[j] = (_Float16)t[c4 * 4 + j][row];
        *(f16x4*)&WT[(size_t)(o0 + row) * 256 + i0 + c4 * 4] = v;
    }
}

// ---------------------------------------------------------------------------
// bias_pair -> MFMA-fragment order, PRESCALED to log2 domain with the -4
// stability offset folded in: frag = (bp - 4) * log2(e).
// frag[((h*32+qt)*32+kt)*256 + lane*4 + reg] = f(bias_pair[h][qt*16+l15][kt*16+quad*4+reg])
// ---------------------------------------------------------------------------
__global__ __launch_bounds__(256) void bpfrag_kernel(
    const float* __restrict__ bias_pair, float* __restrict__ frag)
{
    __shared__ float t[64][68];
    const int qb = blockIdx.x, kb = blockIdx.y, h = blockIdx.z;
    const int tid = threadIdx.x;
    #pragma unroll
    for (int i = 0; i < 4; ++i) {
        const int idx = tid + i * 256;
        const int r = idx >> 4, c4 = idx & 15;
        *(float4*)&t[r][c4 * 4] = *(const float4*)
            &bias_pair[((size_t)h * QLEN + qb * 64 + r) * KLEN + kb * 64 + c4 * 4];
    }
    __syncthreads();
    const int lane = tid & 63, w = tid >> 6;
    const int l15 = lane & 15, quad = lane >> 4;
    const int qt = qb * 4 + w;
    #pragma unroll
    for (int kt2 = 0; kt2 < 4; ++kt2) {
        const int kt = kb * 4 + kt2;
        float4 v;
        v.x = (t[w * 16 + l15][kt2 * 16 + quad * 4 + 0] - 4.0f) * L2E;
        v.y = (t[w * 16 + l15][kt2 * 16 + quad * 4 + 1] - 4.0f) * L2E;
        v.z = (t[w * 16 + l15][kt2 * 16 + quad * 4 + 2] - 4.0f) * L2E;
        v.w = (t[w * 16 + l15][kt2 * 16 + quad * 4 + 3] - 4.0f) * L2E;
        *(float4*)&frag[(((size_t)(h * 32 + qt) * 32) + kt) * 256 + lane * 4] = v;
    }
}

// ---------------------------------------------------------------------------
// bias_mask prescale: bm' = bm * log2(e).  64*512 = 32768 floats.
// ---------------------------------------------------------------------------
__global__ __launch_bounds__(256) void bmscale_kernel(
    const float* __restrict__ bm, float* __restrict__ o)
{
    const int i = blockIdx.x * 256 + threadIdx.x;
    float4 v = *(const float4*)(bm + (size_t)i * 4);
    v.x *= L2E; v.y *= L2E; v.z *= L2E; v.w *= L2E;
    *(float4*)(o + (size_t)i * 4) = v;
}

// ---------------------------------------------------------------------------
// Flatmm-style fused projection GEMM (unchanged structure from r2).
// mode 0=q (scale * log2e now), 1=g, 2=k, 3=v->vT.
// ---------------------------------------------------------------------------
__global__ __launch_bounds__(256, 2) void proj_gemm_kernel(
    const float* __restrict__ q_x, const float* __restrict__ k_x,
    const float* __restrict__ v_x, const _Float16* __restrict__ wT,
    const float* __restrict__ bg,
    _Float16* __restrict__ oq, _Float16* __restrict__ ok,
    _Float16* __restrict__ ovT, _Float16* __restrict__ og)
{
    __shared__ __attribute__((aligned(16))) float A_s[2][32 * 256];  // 64 KB

    const int combo = blockIdx.x >> 6;         // 0..7
    const int blk   = blockIdx.x & 63;
    const int mode  = combo >> 1;              // 0=q,1=g,2=k,3=v
    const int nhalf = combo & 1;
    const float* A = (mode <= 1) ? q_x : (mode == 2) ? k_x : v_x;
    const _Float16* BT = wT + (size_t)mode * 65536;

    const int tid  = threadIdx.x;
    const int lane = tid & 63, w = tid >> 6;
    const int l15  = lane & 15, quad = lane >> 4;
    const int nw   = nhalf * 128 + w * 32;     // wave's 32-col base in [0,256)

    // B resident in VGPRs: bfr[nt][ks] covers col = nw+nt*16+l15, k = ks*32+quad*8..+7
    f16x8 bfr[2][8];
    #pragma unroll
    for (int nt = 0; nt < 2; ++nt)
        #pragma unroll
        for (int ks = 0; ks < 8; ++ks)
            bfr[nt][ks] = *(const f16x8*)(BT +
                (size_t)(nw + nt * 16 + l15) * 256 + ks * 32 + quad * 8);

    float bgv[2] = {0.f, 0.f};
    if (mode == 1) { bgv[0] = bg[nw + l15]; bgv[1] = bg[nw + 16 + l15]; }

    const int row_base = blk * 512;            // 16 panels x 32 rows per block

    f32x4 acc[2][2];
    #pragma unroll
    for (int mt = 0; mt < 2; ++mt)
        #pragma unroll
        for (int nt = 0; nt < 2; ++nt) acc[mt][nt] = (f32x4){0.f, 0.f, 0.f, 0.f};

    auto stage = [&](int panel, int buf) {
        const int row0 = row_base + panel * 32;
        #pragma unroll
        for (int j = 0; j < 8; ++j) {
            const int p = tid + j * 256;       // 16B-chunk id 0..2047
            const int r = p >> 6, c = p & 63;
            const int cl = (c & ~7) | ((c & 7) ^ (r & 7));
            gload16(A + (size_t)(row0 + r) * 256 + cl * 4, &A_s[buf][p * 4]);
        }
    };

    stage(0, 0);
    __syncthreads();

    for (int i = 0; i < 16; ++i) {
        if (i < 15) stage(i + 1, (i + 1) & 1);
        const int buf = i & 1;

        #pragma unroll
        for (int ks = 0; ks < 8; ++ks) {
            f16x8 af[2];
            #pragma unroll
            for (int mt = 0; mt < 2; ++mt) {
                const int r  = mt * 16 + l15;
                const int x0 = ks * 8 + ((quad * 2 + 0) ^ (r & 7));
                const int x1 = ks * 8 + ((quad * 2 + 1) ^ (r & 7));
                const f32x4 a0 = *(const f32x4*)&A_s[buf][(r * 64 + x0) * 4];
                const f32x4 a1 = *(const f32x4*)&A_s[buf][(r * 64 + x1) * 4];
                f16x8 v;
                v[0] = (_Float16)a0[0]; v[1] = (_Float16)a0[1];
                v[2] = (_Float16)a0[2]; v[3] = (_Float16)a0[3];
                v[4] = (_Float16)a1[0]; v[5] = (_Float16)a1[1];
                v[6] = (_Float16)a1[2]; v[7] = (_Float16)a1[3];
                af[mt] = v;
            }
            #pragma unroll
            for (int mt = 0; mt < 2; ++mt)
                #pragma unroll
                for (int nt = 0; nt < 2; ++nt)
                    acc[mt][nt] = __builtin_amdgcn_mfma_f32_16x16x32_f16(
                        af[mt], bfr[nt][ks], acc[mt][nt], 0, 0, 0);
        }

        const int row0 = row_base + i * 32;
        if (mode == 3) {
            #pragma unroll
            for (int mt = 0; mt < 2; ++mt) {
                #pragma unroll
                for (int nt = 0; nt < 2; ++nt) {
                    const int col  = nw + nt * 16 + l15;
                    const int rowg = row0 + mt * 16 + quad * 4;
                    const int nn = rowg >> 9, kpos = rowg & 511;
                    f16x4 st;
                    #pragma unroll
                    for (int reg = 0; reg < 4; ++reg) st[reg] = (_Float16)acc[mt][nt][reg];
                    *(f16x4*)&ovT[((size_t)(nn * 256 + col)) * 512 + kpos] = st;
                }
            }
        } else {
            _Float16* C = (mode == 0) ? oq : (mode == 1) ? og : ok;
            #pragma unroll
            for (int mt = 0; mt < 2; ++mt) {
                #pragma unroll
                for (int nt = 0; nt < 2; ++nt) {
                    const int col  = nw + nt * 16 + l15;
                    const int rowg = row0 + mt * 16 + quad * 4;
                    #pragma unroll
                    for (int reg = 0; reg < 4; ++reg) {
                        float x = acc[mt][nt][reg];
                        // q-scale = (1/sqrt(32)) * log2(e): attention runs in log2 domain
                        if (mode == 0) x *= 0.2550348614f;
                        if (mode == 1) { x += bgv[nt]; x = 1.0f / (1.0f + __expf(-x)); }
                        C[(size_t)(rowg + reg) * HIDDIM + col] = (_Float16)x;
                    }
                }
            }
        }
        #pragma unroll
        for (int mt = 0; mt < 2; ++mt)
            #pragma unroll
            for (int nt = 0; nt < 2; ++nt) acc[mt][nt] = (f32x4){0.f, 0.f, 0.f, 0.f};

        __syncthreads();
    }
}

// ---------------------------------------------------------------------------
// Output projection GEMM, flatmm-style (same skeleton as proj, fp16 A).
// Grid 512: blk = x & 255 (128 rows, 4 panels of 32), nhalf = x >> 8.
// wo^T resident in VGPRs; A (attention output, fp16) streams through
// double-buffered LDS (2 x 16 KB) with XOR-pre-swizzled source.
// ---------------------------------------------------------------------------
__global__ __launch_bounds__(256, 2) void outproj_kernel(
    const _Float16* __restrict__ Ain, const _Float16* __restrict__ BT,
    const float* __restrict__ bias, float* __restrict__ Cout)
{
    __shared__ __attribute__((aligned(16))) _Float16 A_s[2][32 * 256];  // 2 x 16 KB

    const int blk   = blockIdx.x & 255;
    const int nhalf = blockIdx.x >> 8;
    const int tid  = threadIdx.x;
    const int lane = tid & 63, w = tid >> 6;
    const int l15  = lane & 15, quad = lane >> 4;
    const int nw   = nhalf * 128 + w * 32;

    f16x8 bfr[2][8];
    #pragma unroll
    for (int nt = 0; nt < 2; ++nt)
        #pragma unroll
        for (int ks = 0; ks < 8; ++ks)
            bfr[nt][ks] = *(const f16x8*)(BT +
                (size_t)(nw + nt * 16 + l15) * 256 + ks * 32 + quad * 8);

    const float bv[2] = { bias[nw + l15], bias[nw + 16 + l15] };
    const int row_base = blk * 128;            // 4 panels x 32 rows

    f32x4 acc[2][2];
    #pragma unroll
    for (int mt = 0; mt < 2; ++mt)
        #pragma unroll
        for (int nt = 0; nt < 2; ++nt) acc[mt][nt] = (f32x4){0.f, 0.f, 0.f, 0.f};

    // Panel = 32 rows x 256 f16 = 16 KB = 1024 16B-chunks; 32 chunks/row.
    auto stage = [&](int panel, int buf) {
        const int row0 = row_base + panel * 32;
        #pragma unroll
        for (int j = 0; j < 4; ++j) {
            const int p = tid + j * 256;       // chunk id 0..1023
            const int r = p >> 5, c = p & 31;
            const int cl = (c & ~7) | ((c & 7) ^ (r & 7));
            gload16(Ain + (size_t)(row0 + r) * 256 + cl * 8, &A_s[buf][p * 8]);
        }
    };

    stage(0, 0);
    __syncthreads();

    for (int i = 0; i < 4; ++i) {
        if (i < 3) stage(i + 1, (i + 1) & 1);
        const int buf = i & 1;

        #pragma unroll
        for (int ks = 0; ks < 8; ++ks) {
            f16x8 af[2];
            #pragma unroll
            for (int mt = 0; mt < 2; ++mt) {
                const int r = mt * 16 + l15;
                const int c = (ks * 4 + quad) ^ (r & 7);   // 32 chunks/row, low-3 XOR
                af[mt] = *(const f16x8*)&A_s[buf][r * 256 + c * 8];
            }
            #pragma unroll
            for (int mt = 0; mt < 2; ++mt)
                #pragma unroll
                for (int nt = 0; nt < 2; ++nt)
                    acc[mt][nt] = __builtin_amdgcn_mfma_f32_16x16x32_f16(
                        af[mt], bfr[nt][ks], acc[mt][nt], 0, 0, 0);
        }

        const int row0 = row_base + i * 32;
        #pragma unroll
        for (int mt = 0; mt < 2; ++mt) {
            #pragma unroll
            for (int nt = 0; nt < 2; ++nt) {
                const int col  = nw + nt * 16 + l15;
                const int rowg = row0 + mt * 16 + quad * 4;
                #pragma unroll
                for (int reg = 0; reg < 4; ++reg)
                    Cout[(size_t)(rowg + reg) * HIDDIM + col] = acc[mt][nt][reg] + bv[nt];
            }
        }
        #pragma unroll
        for (int mt = 0; mt < 2; ++mt)
            #pragma unroll
            for (int nt = 0; nt < 2; ++nt) acc[mt][nt] = (f32x4){0.f, 0.f, 0.f, 0.f};

        __syncthreads();
    }
}

// ---------------------------------------------------------------------------
// MFMA flash attention. Changes vs r2:
//  - biases folded into the S-MFMA C-operand (c_init = bm' + bp'), so the
//    matrix pipe performs the adds;
//  - log2-domain: q prescaled by log2e at proj, bp'/bm' prescaled ->
//    p = v_exp_f32(s) directly (no per-element mul/adds);
//  - one-ahead register prefetch of bm'/bp' (kti addressing crosses chunks);
//  - s_setprio(1) around MFMA clusters (T5).
// ---------------------------------------------------------------------------
__global__ __launch_bounds__(256, 4) void attn_kernel(
    const _Float16* __restrict__ qb, const _Float16* __restrict__ kb,
    const _Float16* __restrict__ vT, const _Float16* __restrict__ gb,
    _Float16* __restrict__ ob,
    const float* __restrict__ bm2, const float* __restrict__ bp_frag)
{
    __shared__ _Float16 k_s[128][40];    // 80B rows ≡ 20 banks mod 32
    __shared__ _Float16 v_s[32][136];    // [c][k], 272B rows ≡ 4 banks mod 32

    const int n    = blockIdx.x;
    const int h    = blockIdx.y;
    const int q0   = blockIdx.z * 128;
    const int tid  = threadIdx.x;
    const int lane = tid & 63;
    const int wq   = tid >> 6;            // wave id: q-band = wq*32
    const int l15  = lane & 15;
    const int quad = lane >> 4;

    f16x8 qf[2];
    #pragma unroll
    for (int qt = 0; qt < 2; ++qt)
        qf[qt] = *(const f16x8*)(qb +
            (size_t)(n * QLEN + q0 + wq * 32 + qt * 16 + l15) * HIDDIM + h * CH + quad * 8);

    const float* bpf = bp_frag +
        ((size_t)(h * 32 + blockIdx.z * 8 + wq * 2) * 32) * 256 + lane * 4;
    const float* bmb = bm2 + n * KLEN + quad * 4;

    f32x4 o_acc[2][2];
    float l_lane[2] = {0.f, 0.f};
    #pragma unroll
    for (int qt = 0; qt < 2; ++qt)
        #pragma unroll
        for (int ct = 0; ct < 2; ++ct) o_acc[qt][ct] = (f32x4){0.f, 0.f, 0.f, 0.f};

    // Prefetch bias fragments for kti = 0 (L2-resident; latency hidden under staging).
    float4 bmv = *(const float4*)bmb;
    float4 bp0 = *(const float4*)bpf;
    float4 bp1 = *(const float4*)(bpf + 32 * 256);

    for (int ch = 0; ch < 4; ++ch) {
        __syncthreads();   // previous chunk fully consumed
        #pragma unroll
        for (int i = 0; i < 2; ++i) {
            const int idx = tid + i * 256;
            const int r = idx >> 2, c8 = idx & 3;
            *(uint4*)&k_s[r][c8 * 8] = *(const uint4*)
                (kb + (size_t)(n * KLEN + ch * 128 + r) * HIDDIM + h * CH + c8 * 8);
            const int vr = idx >> 4, vs = idx & 15;
            *(uint4*)&v_s[vr][vs * 8] = *(const uint4*)
                (vT + ((size_t)(n * HEADS + h) * CH + vr) * KLEN + ch * 128 + vs * 8);
        }
        __syncthreads();

        #pragma unroll
        for (int kt = 0; kt < 8; ++kt) {
            const int kti = ch * 8 + kt;
            const f16x8 kf = *(const f16x8*)&k_s[kt * 16 + l15][quad * 8];
            // biases enter through the MFMA C-operand
            f32x4 c0, c1;
            c0[0] = bmv.x + bp0.x; c0[1] = bmv.y + bp0.y;
            c0[2] = bmv.z + bp0.z; c0[3] = bmv.w + bp0.w;
            c1[0] = bmv.x + bp1.x; c1[1] = bmv.y + bp1.y;
            c1[2] = bmv.z + bp1.z; c1[3] = bmv.w + bp1.w;
            __builtin_amdgcn_s_setprio(1);
            const f32x4 s0 = __builtin_amdgcn_mfma_f32_16x16x32_f16(kf, qf[0], c0, 0, 0, 0);
            const f32x4 s1 = __builtin_amdgcn_mfma_f32_16x16x32_f16(kf, qf[1], c1, 0, 0, 0);
            __builtin_amdgcn_s_setprio(0);
            if (kti < 31) {   // one-ahead prefetch (flows across chunk boundary)
                bmv = *(const float4*)(bmb + (size_t)(kti + 1) * 16);
                bp0 = *(const float4*)(bpf + (size_t)(kti + 1) * 256);
                bp1 = *(const float4*)(bpf + (size_t)(32 + kti + 1) * 256);
            }
            const f16x4 bv0 = *(const f16x4*)&v_s[l15][kt * 16 + quad * 4];
            const f16x4 bv1 = *(const f16x4*)&v_s[16 + l15][kt * 16 + quad * 4];
            #pragma unroll
            for (int qt = 0; qt < 2; ++qt) {
                const f32x4 s = qt ? s1 : s0;
                const float p0 = exp2_fast(s[0]);
                const float p1 = exp2_fast(s[1]);
                const float p2 = exp2_fast(s[2]);
                const float p3 = exp2_fast(s[3]);
                l_lane[qt] += (p0 + p1) + (p2 + p3);
                union { f16x4 v; fp16x2 h[2]; } u;
                u.h[0] = __builtin_amdgcn_cvt_pkrtz(p0, p1);
                u.h[1] = __builtin_amdgcn_cvt_pkrtz(p2, p3);
                __builtin_amdgcn_s_setprio(1);
                o_acc[qt][0] = __builtin_amdgcn_mfma_f32_16x16x16f16(u.v, bv0, o_acc[qt][0], 0, 0, 0);
                o_acc[qt][1] = __builtin_amdgcn_mfma_f32_16x16x16f16(u.v, bv1, o_acc[qt][1], 0, 0, 0);
                __builtin_amdgcn_s_setprio(0);
            }
        }
    }

    float invl[2][4];
    #pragma unroll
    for (int qt = 0; qt < 2; ++qt) {
        float lf = l_lane[qt];
        lf += __shfl_xor(lf, 16);
        lf += __shfl_xor(lf, 32);
        #pragma unroll
        for (int reg = 0; reg < 4; ++reg)
            invl[qt][reg] = 1.0f / __shfl(lf, quad * 4 + reg);
    }

    #pragma unroll
    for (int qt = 0; qt < 2; ++qt) {
        #pragma unroll
        for (int ct = 0; ct < 2; ++ct) {
            #pragma unroll
            for (int reg = 0; reg < 4; ++reg) {
                const int row = q0 + wq * 32 + qt * 16 + quad * 4 + reg;
                const size_t idx = (size_t)(n * QLEN + row) * HIDDIM + h * CH + ct * 16 + l15;
                const float g = (float)gb[idx];
                ob[idx] = (_Float16)(o_acc[qt][ct][reg] * invl[qt][reg] * g);
            }
        }
    }
}

// ---------------------------------------------------------------------------
// Launch: wcast + bpfrag + bmscale -> flatmm projections -> attention ->
// flatmm output projection.
// Workspace: 5 x 16.8 MB fp16 + 0.66 MB weights + 8.4 MB bp_frag + 0.13 MB bm2
// ---------------------------------------------------------------------------
extern "C" void kernel_launch(void* const* d_in, const int* in_sizes, int n_in,
                              void* d_out, int out_size, void* d_ws, size_t ws_size,
                              hipStream_t stream)
{
    const float* q_x       = (const float*)d_in[0];
    const float* k_x       = (const float*)d_in[1];
    const float* v_x       = (const float*)d_in[2];
    const float* bias_mask = (const float*)d_in[3];
    const float* bias_pair = (const float*)d_in[4];
    const float* wq        = (const float*)d_in[5];
    const float* wk        = (const float*)d_in[6];
    const float* wv        = (const float*)d_in[7];
    const float* wg        = (const float*)d_in[8];
    const float* bg        = (const float*)d_in[9];
    const float* wo        = (const float*)d_in[10];
    const float* bo        = (const float*)d_in[11];
    float* out = (float*)d_out;

    const size_t BUF = (size_t)M_TOTAL * HIDDIM;   // 8388608 elems
    _Float16* ws_q  = (_Float16*)d_ws;
    _Float16* ws_k  = ws_q + BUF;
    _Float16* ws_vT = ws_k + BUF;
    _Float16* ws_g  = ws_vT + BUF;
    _Float16* ws_o  = ws_g + BUF;
    _Float16* wT    = ws_o + BUF;                  // 5 x 256*256 fp16
    float*    bpf   = (float*)(wT + 5 * 65536);    // 8 x 512 x 512 fp32 frag-ordered
    float*    bm2   = bpf + (size_t)8 * 512 * 512; // 64 x 512 fp32, log2-scaled

    // slab order q, g, k, v, o
    wcast_kernel<<<dim3(4, 4, 5), 256, 0, stream>>>(wq, wg, wk, wv, wo, wT);
    bpfrag_kernel<<<dim3(8, 8, 8), 256, 0, stream>>>(bias_pair, bpf);
    bmscale_kernel<<<dim3(32), 256, 0, stream>>>(bias_mask, bm2);

    proj_gemm_kernel<<<dim3(512), 256, 0, stream>>>(
        q_x, k_x, v_x, wT, bg, ws_q, ws_k, ws_vT, ws_g);

    attn_kernel<<<dim3(NSEQ, HEADS, QLEN / 128), 256, 0, stream>>>(
        ws_q, ws_k, ws_vT, ws_g, ws_o, bm2, bpf);

    outproj_kernel<<<dim3(512), 256, 0, stream>>>(
        ws_o, wT + 4 * 65536, bo, out);
}

// Round 4
// 252.756 us; speedup vs baseline: 1.6135x; 1.6135x over previous
//
#include <hip/hip_runtime.h>
#include <math.h>

// Problem constants (reference: B=1, N=64, Q=K=512, C_Q=C_K=C_V=256, H=8, c=32)
#define NSEQ   64
#define QLEN   512
#define KLEN   512
#define CIN    256
#define HEADS  8
#define CH     32
#define HIDDIM 256
#define M_TOTAL (NSEQ * QLEN)   // 32768 rows for all projections
#define L2E    1.4426950408889634f

typedef _Float16 f16x8 __attribute__((ext_vector_type(8)));
typedef _Float16 f16x4 __attribute__((ext_vector_type(4)));
typedef __fp16   fp16x2 __attribute__((ext_vector_type(2)));   // cvt_pkrtz native type
typedef float    f32x4 __attribute__((ext_vector_type(4)));

// Async global->LDS, 16B per lane. Dest must be linear in lane order;
// swizzle is applied on the GLOBAL source and mirrored on the LDS read (G21).
__device__ __forceinline__ void gload16(const void* g, void* l) {
    __builtin_amdgcn_global_load_lds(
        (const __attribute__((address_space(1))) void*)g,
        (__attribute__((address_space(3))) void*)l, 16, 0, 0);
}

// exp2 without the OCML edge-case fixup (args are well within range).
__device__ __forceinline__ float exp2_fast(float x) {
#if __has_builtin(__builtin_amdgcn_exp2f)
    return __builtin_amdgcn_exp2f(x);
#else
    float r; asm("v_exp_f32 %0, %1" : "=v"(r) : "v"(x)); return r;
#endif
}

// ---------------------------------------------------------------------------
// Weight transpose+cast: W[256 in][256 out] fp32 -> WT[256 out][256 in] fp16.
// Slab order: 0=wq, 1=wg, 2=wk, 3=wv, 4=wo.
// ---------------------------------------------------------------------------
__global__ __launch_bounds__(256) void wcast_kernel(
    const float* __restrict__ w0, const float* __restrict__ w1,
    const float* __restrict__ w2, const float* __restrict__ w3,
    const float* __restrict__ w4, _Float16* __restrict__ wt)
{
    __shared__ float t[64][65];
    const float* W;
    switch (blockIdx.z) {
        case 0: W = w0; break; case 1: W = w1; break;
        case 2: W = w2; break; case 3: W = w3; break;
        default: W = w4;
    }
    _Float16* WT = wt + (size_t)blockIdx.z * 65536;
    const int i0 = blockIdx.x * 64, o0 = blockIdx.y * 64;
    const int tid = threadIdx.x;
    const int rr = tid >> 4, c4 = tid & 15;
    #pragma unroll
    for (int i = 0; i < 4; ++i) {
        const int row = rr + i * 16;
        *(float4*)&t[row][c4 * 4] = *(const float4*)&W[(size_t)(i0 + row) * 256 + o0 + c4 * 4];
    }
    __syncthreads();
    #pragma unroll
    for (int i = 0; i < 4; ++i) {
        const int row = rr + i * 16;            // out-dim row
        f16x4 v;
        #pragma unroll
        for (int j = 0; j < 4; ++j) v[j] = (_Float16)t[c4 * 4 + j][row];
        *(f16x4*)&WT[(size_t)(o0 + row) * 256 + i0 + c4 * 4] = v;
    }
}

// ---------------------------------------------------------------------------
// bias_pair -> MFMA-fragment order, PRESCALED to log2 domain with the -4
// stability offset folded in: frag = (bp - 4) * log2(e).
// ---------------------------------------------------------------------------
__global__ __launch_bounds__(256) void bpfrag_kernel(
    const float* __restrict__ bias_pair, float* __restrict__ frag)
{
    __shared__ float t[64][68];
    const int qb = blockIdx.x, kb = blockIdx.y, h = blockIdx.z;
    const int tid = threadIdx.x;
    #pragma unroll
    for (int i = 0; i < 4; ++i) {
        const int idx = tid + i * 256;
        const int r = idx >> 4, c4 = idx & 15;
        *(float4*)&t[r][c4 * 4] = *(const float4*)
            &bias_pair[((size_t)h * QLEN + qb * 64 + r) * KLEN + kb * 64 + c4 * 4];
    }
    __syncthreads();
    const int lane = tid & 63, w = tid >> 6;
    const int l15 = lane & 15, quad = lane >> 4;
    const int qt = qb * 4 + w;
    #pragma unroll
    for (int kt2 = 0; kt2 < 4; ++kt2) {
        const int kt = kb * 4 + kt2;
        float4 v;
        v.x = (t[w * 16 + l15][kt2 * 16 + quad * 4 + 0] - 4.0f) * L2E;
        v.y = (t[w * 16 + l15][kt2 * 16 + quad * 4 + 1] - 4.0f) * L2E;
        v.z = (t[w * 16 + l15][kt2 * 16 + quad * 4 + 2] - 4.0f) * L2E;
        v.w = (t[w * 16 + l15][kt2 * 16 + quad * 4 + 3] - 4.0f) * L2E;
        *(float4*)&frag[(((size_t)(h * 32 + qt) * 32) + kt) * 256 + lane * 4] = v;
    }
}

// ---------------------------------------------------------------------------
// bias_mask prescale: bm' = bm * log2(e).  64*512 = 32768 floats.
// ---------------------------------------------------------------------------
__global__ __launch_bounds__(256) void bmscale_kernel(
    const float* __restrict__ bm, float* __restrict__ o)
{
    const int i = blockIdx.x * 256 + threadIdx.x;
    float4 v = *(const float4*)(bm + (size_t)i * 4);
    v.x *= L2E; v.y *= L2E; v.z *= L2E; v.w *= L2E;
    *(float4*)(o + (size_t)i * 4) = v;
}

// ---------------------------------------------------------------------------
// Flatmm-style fused projection GEMM (unchanged).
// mode 0=q (scale * log2e), 1=g, 2=k, 3=v->vT.
// ---------------------------------------------------------------------------
__global__ __launch_bounds__(256, 2) void proj_gemm_kernel(
    const float* __restrict__ q_x, const float* __restrict__ k_x,
    const float* __restrict__ v_x, const _Float16* __restrict__ wT,
    const float* __restrict__ bg,
    _Float16* __restrict__ oq, _Float16* __restrict__ ok,
    _Float16* __restrict__ ovT, _Float16* __restrict__ og)
{
    __shared__ __attribute__((aligned(16))) float A_s[2][32 * 256];  // 64 KB

    const int combo = blockIdx.x >> 6;         // 0..7
    const int blk   = blockIdx.x & 63;
    const int mode  = combo >> 1;              // 0=q,1=g,2=k,3=v
    const int nhalf = combo & 1;
    const float* A = (mode <= 1) ? q_x : (mode == 2) ? k_x : v_x;
    const _Float16* BT = wT + (size_t)mode * 65536;

    const int tid  = threadIdx.x;
    const int lane = tid & 63, w = tid >> 6;
    const int l15  = lane & 15, quad = lane >> 4;
    const int nw   = nhalf * 128 + w * 32;     // wave's 32-col base in [0,256)

    f16x8 bfr[2][8];
    #pragma unroll
    for (int nt = 0; nt < 2; ++nt)
        #pragma unroll
        for (int ks = 0; ks < 8; ++ks)
            bfr[nt][ks] = *(const f16x8*)(BT +
                (size_t)(nw + nt * 16 + l15) * 256 + ks * 32 + quad * 8);

    float bgv[2] = {0.f, 0.f};
    if (mode == 1) { bgv[0] = bg[nw + l15]; bgv[1] = bg[nw + 16 + l15]; }

    const int row_base = blk * 512;            // 16 panels x 32 rows per block

    f32x4 acc[2][2];
    #pragma unroll
    for (int mt = 0; mt < 2; ++mt)
        #pragma unroll
        for (int nt = 0; nt < 2; ++nt) acc[mt][nt] = (f32x4){0.f, 0.f, 0.f, 0.f};

    auto stage = [&](int panel, int buf) {
        const int row0 = row_base + panel * 32;
        #pragma unroll
        for (int j = 0; j < 8; ++j) {
            const int p = tid + j * 256;       // 16B-chunk id 0..2047
            const int r = p >> 6, c = p & 63;
            const int cl = (c & ~7) | ((c & 7) ^ (r & 7));
            gload16(A + (size_t)(row0 + r) * 256 + cl * 4, &A_s[buf][p * 4]);
        }
    };

    stage(0, 0);
    __syncthreads();

    for (int i = 0; i < 16; ++i) {
        if (i < 15) stage(i + 1, (i + 1) & 1);
        const int buf = i & 1;

        #pragma unroll
        for (int ks = 0; ks < 8; ++ks) {
            f16x8 af[2];
            #pragma unroll
            for (int mt = 0; mt < 2; ++mt) {
                const int r  = mt * 16 + l15;
                const int x0 = ks * 8 + ((quad * 2 + 0) ^ (r & 7));
                const int x1 = ks * 8 + ((quad * 2 + 1) ^ (r & 7));
                const f32x4 a0 = *(const f32x4*)&A_s[buf][(r * 64 + x0) * 4];
                const f32x4 a1 = *(const f32x4*)&A_s[buf][(r * 64 + x1) * 4];
                f16x8 v;
                v[0] = (_Float16)a0[0]; v[1] = (_Float16)a0[1];
                v[2] = (_Float16)a0[2]; v[3] = (_Float16)a0[3];
                v[4] = (_Float16)a1[0]; v[5] = (_Float16)a1[1];
                v[6] = (_Float16)a1[2]; v[7] = (_Float16)a1[3];
                af[mt] = v;
            }
            #pragma unroll
            for (int mt = 0; mt < 2; ++mt)
                #pragma unroll
                for (int nt = 0; nt < 2; ++nt)
                    acc[mt][nt] = __builtin_amdgcn_mfma_f32_16x16x32_f16(
                        af[mt], bfr[nt][ks], acc[mt][nt], 0, 0, 0);
        }

        const int row0 = row_base + i * 32;
        if (mode == 3) {
            #pragma unroll
            for (int mt = 0; mt < 2; ++mt) {
                #pragma unroll
                for (int nt = 0; nt < 2; ++nt) {
                    const int col  = nw + nt * 16 + l15;
                    const int rowg = row0 + mt * 16 + quad * 4;
                    const int nn = rowg >> 9, kpos = rowg & 511;
                    f16x4 st;
                    #pragma unroll
                    for (int reg = 0; reg < 4; ++reg) st[reg] = (_Float16)acc[mt][nt][reg];
                    *(f16x4*)&ovT[((size_t)(nn * 256 + col)) * 512 + kpos] = st;
                }
            }
        } else {
            _Float16* C = (mode == 0) ? oq : (mode == 1) ? og : ok;
            #pragma unroll
            for (int mt = 0; mt < 2; ++mt) {
                #pragma unroll
                for (int nt = 0; nt < 2; ++nt) {
                    const int col  = nw + nt * 16 + l15;
                    const int rowg = row0 + mt * 16 + quad * 4;
                    #pragma unroll
                    for (int reg = 0; reg < 4; ++reg) {
                        float x = acc[mt][nt][reg];
                        // q-scale = (1/sqrt(32)) * log2(e): attention runs in log2 domain
                        if (mode == 0) x *= 0.2550348614f;
                        if (mode == 1) { x += bgv[nt]; x = 1.0f / (1.0f + __expf(-x)); }
                        C[(size_t)(rowg + reg) * HIDDIM + col] = (_Float16)x;
                    }
                }
            }
        }
        #pragma unroll
        for (int mt = 0; mt < 2; ++mt)
            #pragma unroll
            for (int nt = 0; nt < 2; ++nt) acc[mt][nt] = (f32x4){0.f, 0.f, 0.f, 0.f};

        __syncthreads();
    }
}

// ---------------------------------------------------------------------------
// Output projection GEMM, flatmm-style (unchanged from r3).
// ---------------------------------------------------------------------------
__global__ __launch_bounds__(256, 2) void outproj_kernel(
    const _Float16* __restrict__ Ain, const _Float16* __restrict__ BT,
    const float* __restrict__ bias, float* __restrict__ Cout)
{
    __shared__ __attribute__((aligned(16))) _Float16 A_s[2][32 * 256];  // 2 x 16 KB

    const int blk   = blockIdx.x & 255;
    const int nhalf = blockIdx.x >> 8;
    const int tid  = threadIdx.x;
    const int lane = tid & 63, w = tid >> 6;
    const int l15  = lane & 15, quad = lane >> 4;
    const int nw   = nhalf * 128 + w * 32;

    f16x8 bfr[2][8];
    #pragma unroll
    for (int nt = 0; nt < 2; ++nt)
        #pragma unroll
        for (int ks = 0; ks < 8; ++ks)
            bfr[nt][ks] = *(const f16x8*)(BT +
                (size_t)(nw + nt * 16 + l15) * 256 + ks * 32 + quad * 8);

    const float bv[2] = { bias[nw + l15], bias[nw + 16 + l15] };
    const int row_base = blk * 128;            // 4 panels x 32 rows

    f32x4 acc[2][2];
    #pragma unroll
    for (int mt = 0; mt < 2; ++mt)
        #pragma unroll
        for (int nt = 0; nt < 2; ++nt) acc[mt][nt] = (f32x4){0.f, 0.f, 0.f, 0.f};

    auto stage = [&](int panel, int buf) {
        const int row0 = row_base + panel * 32;
        #pragma unroll
        for (int j = 0; j < 4; ++j) {
            const int p = tid + j * 256;       // chunk id 0..1023
            const int r = p >> 5, c = p & 31;
            const int cl = (c & ~7) | ((c & 7) ^ (r & 7));
            gload16(Ain + (size_t)(row0 + r) * 256 + cl * 8, &A_s[buf][p * 8]);
        }
    };

    stage(0, 0);
    __syncthreads();

    for (int i = 0; i < 4; ++i) {
        if (i < 3) stage(i + 1, (i + 1) & 1);
        const int buf = i & 1;

        #pragma unroll
        for (int ks = 0; ks < 8; ++ks) {
            f16x8 af[2];
            #pragma unroll
            for (int mt = 0; mt < 2; ++mt) {
                const int r = mt * 16 + l15;
                const int c = (ks * 4 + quad) ^ (r & 7);   // 32 chunks/row, low-3 XOR
                af[mt] = *(const f16x8*)&A_s[buf][r * 256 + c * 8];
            }
            #pragma unroll
            for (int mt = 0; mt < 2; ++mt)
                #pragma unroll
                for (int nt = 0; nt < 2; ++nt)
                    acc[mt][nt] = __builtin_amdgcn_mfma_f32_16x16x32_f16(
                        af[mt], bfr[nt][ks], acc[mt][nt], 0, 0, 0);
        }

        const int row0 = row_base + i * 32;
        #pragma unroll
        for (int mt = 0; mt < 2; ++mt) {
            #pragma unroll
            for (int nt = 0; nt < 2; ++nt) {
                const int col  = nw + nt * 16 + l15;
                const int rowg = row0 + mt * 16 + quad * 4;
                #pragma unroll
                for (int reg = 0; reg < 4; ++reg)
                    Cout[(size_t)(rowg + reg) * HIDDIM + col] = acc[mt][nt][reg] + bv[nt];
            }
        }
        #pragma unroll
        for (int mt = 0; mt < 2; ++mt)
            #pragma unroll
            for (int nt = 0; nt < 2; ++nt) acc[mt][nt] = (f32x4){0.f, 0.f, 0.f, 0.f};

        __syncthreads();
    }
}

// ---------------------------------------------------------------------------
// MFMA flash attention. r4: bias C-operand fold + log2-domain exp2 KEPT;
// the r3 cross-iteration register prefetch REMOVED (it pushed live regs
// past the allocator budget -> 366 MB scratch spill, 200us). Bias float4s
// are loaded inline per iteration (L2-resident, hidden by 8 blocks/CU TLP).
// ---------------------------------------------------------------------------
__global__ __launch_bounds__(256, 4) void attn_kernel(
    const _Float16* __restrict__ qb, const _Float16* __restrict__ kb,
    const _Float16* __restrict__ vT, const _Float16* __restrict__ gb,
    _Float16* __restrict__ ob,
    const float* __restrict__ bm2, const float* __restrict__ bp_frag)
{
    __shared__ _Float16 k_s[128][40];    // 80B rows ≡ 20 banks mod 32
    __shared__ _Float16 v_s[32][136];    // [c][k], 272B rows ≡ 4 banks mod 32

    const int n    = blockIdx.x;
    const int h    = blockIdx.y;
    const int q0   = blockIdx.z * 128;
    const int tid  = threadIdx.x;
    const int lane = tid & 63;
    const int wq   = tid >> 6;            // wave id: q-band = wq*32
    const int l15  = lane & 15;
    const int quad = lane >> 4;

    f16x8 qf[2];
    #pragma unroll
    for (int qt = 0; qt < 2; ++qt)
        qf[qt] = *(const f16x8*)(qb +
            (size_t)(n * QLEN + q0 + wq * 32 + qt * 16 + l15) * HIDDIM + h * CH + quad * 8);

    const float* bpf = bp_frag +
        ((size_t)(h * 32 + blockIdx.z * 8 + wq * 2) * 32) * 256 + lane * 4;
    const float* bmb = bm2 + n * KLEN + quad * 4;

    f32x4 o_acc[2][2];
    float l_lane[2] = {0.f, 0.f};
    #pragma unroll
    for (int qt = 0; qt < 2; ++qt)
        #pragma unroll
        for (int ct = 0; ct < 2; ++ct) o_acc[qt][ct] = (f32x4){0.f, 0.f, 0.f, 0.f};

    for (int ch = 0; ch < 4; ++ch) {
        __syncthreads();   // previous chunk fully consumed
        #pragma unroll
        for (int i = 0; i < 2; ++i) {
            const int idx = tid + i * 256;
            const int r = idx >> 2, c8 = idx & 3;
            *(uint4*)&k_s[r][c8 * 8] = *(const uint4*)
                (kb + (size_t)(n * KLEN + ch * 128 + r) * HIDDIM + h * CH + c8 * 8);
            const int vr = idx >> 4, vs = idx & 15;
            *(uint4*)&v_s[vr][vs * 8] = *(const uint4*)
                (vT + ((size_t)(n * HEADS + h) * CH + vr) * KLEN + ch * 128 + vs * 8);
        }
        __syncthreads();

        #pragma unroll
        for (int kt = 0; kt < 8; ++kt) {
            const int kti = ch * 8 + kt;
            const f16x8 kf = *(const f16x8*)&k_s[kt * 16 + l15][quad * 8];
            // Inline bias loads (NO cross-iteration register state).
            const float4 bm  = *(const float4*)(bmb + ch * 128 + kt * 16);
            const float4 bp0 = *(const float4*)(bpf + (size_t)kti * 256);
            const float4 bp1 = *(const float4*)(bpf + (size_t)(32 + kti) * 256);
            f32x4 c0, c1;
            c0[0] = bm.x + bp0.x; c0[1] = bm.y + bp0.y;
            c0[2] = bm.z + bp0.z; c0[3] = bm.w + bp0.w;
            c1[0] = bm.x + bp1.x; c1[1] = bm.y + bp1.y;
            c1[2] = bm.z + bp1.z; c1[3] = bm.w + bp1.w;
            __builtin_amdgcn_s_setprio(1);
            const f32x4 s0 = __builtin_amdgcn_mfma_f32_16x16x32_f16(kf, qf[0], c0, 0, 0, 0);
            const f32x4 s1 = __builtin_amdgcn_mfma_f32_16x16x32_f16(kf, qf[1], c1, 0, 0, 0);
            __builtin_amdgcn_s_setprio(0);
            const f16x4 bv0 = *(const f16x4*)&v_s[l15][kt * 16 + quad * 4];
            const f16x4 bv1 = *(const f16x4*)&v_s[16 + l15][kt * 16 + quad * 4];
            #pragma unroll
            for (int qt = 0; qt < 2; ++qt) {
                const f32x4 s = qt ? s1 : s0;
                const float p0 = exp2_fast(s[0]);
                const float p1 = exp2_fast(s[1]);
                const float p2 = exp2_fast(s[2]);
                const float p3 = exp2_fast(s[3]);
                l_lane[qt] += (p0 + p1) + (p2 + p3);
                union { f16x4 v; fp16x2 h[2]; } u;
                u.h[0] = __builtin_amdgcn_cvt_pkrtz(p0, p1);
                u.h[1] = __builtin_amdgcn_cvt_pkrtz(p2, p3);
                __builtin_amdgcn_s_setprio(1);
                o_acc[qt][0] = __builtin_amdgcn_mfma_f32_16x16x16f16(u.v, bv0, o_acc[qt][0], 0, 0, 0);
                o_acc[qt][1] = __builtin_amdgcn_mfma_f32_16x16x16f16(u.v, bv1, o_acc[qt][1], 0, 0, 0);
                __builtin_amdgcn_s_setprio(0);
            }
        }
    }

    float invl[2][4];
    #pragma unroll
    for (int qt = 0; qt < 2; ++qt) {
        float lf = l_lane[qt];
        lf += __shfl_xor(lf, 16);
        lf += __shfl_xor(lf, 32);
        #pragma unroll
        for (int reg = 0; reg < 4; ++reg)
            invl[qt][reg] = 1.0f / __shfl(lf, quad * 4 + reg);
    }

    #pragma unroll
    for (int qt = 0; qt < 2; ++qt) {
        #pragma unroll
        for (int ct = 0; ct < 2; ++ct) {
            #pragma unroll
            for (int reg = 0; reg < 4; ++reg) {
                const int row = q0 + wq * 32 + qt * 16 + quad * 4 + reg;
                const size_t idx = (size_t)(n * QLEN + row) * HIDDIM + h * CH + ct * 16 + l15;
                const float g = (float)gb[idx];
                ob[idx] = (_Float16)(o_acc[qt][ct][reg] * invl[qt][reg] * g);
            }
        }
    }
}

// ---------------------------------------------------------------------------
// Launch: wcast + bpfrag + bmscale -> flatmm projections -> attention ->
// flatmm output projection.
// Workspace: 5 x 16.8 MB fp16 + 0.66 MB weights + 8.4 MB bp_frag + 0.13 MB bm2
// ---------------------------------------------------------------------------
extern "C" void kernel_launch(void* const* d_in, const int* in_sizes, int n_in,
                              void* d_out, int out_size, void* d_ws, size_t ws_size,
                              hipStream_t stream)
{
    const float* q_x       = (const float*)d_in[0];
    const float* k_x       = (const float*)d_in[1];
    const float* v_x       = (const float*)d_in[2];
    const float* bias_mask = (const float*)d_in[3];
    const float* bias_pair = (const float*)d_in[4];
    const float* wq        = (const float*)d_in[5];
    const float* wk        = (const float*)d_in[6];
    const float* wv        = (const float*)d_in[7];
    const float* wg        = (const float*)d_in[8];
    const float* bg        = (const float*)d_in[9];
    const float* wo        = (const float*)d_in[10];
    const float* bo        = (const float*)d_in[11];
    float* out = (float*)d_out;

    const size_t BUF = (size_t)M_TOTAL * HIDDIM;   // 8388608 elems
    _Float16* ws_q  = (_Float16*)d_ws;
    _Float16* ws_k  = ws_q + BUF;
    _Float16* ws_vT = ws_k + BUF;
    _Float16* ws_g  = ws_vT + BUF;
    _Float16* ws_o  = ws_g + BUF;
    _Float16* wT    = ws_o + BUF;                  // 5 x 256*256 fp16
    float*    bpf   = (float*)(wT + 5 * 65536);    // 8 x 512 x 512 fp32 frag-ordered
    float*    bm2   = bpf + (size_t)8 * 512 * 512; // 64 x 512 fp32, log2-scaled

    // slab order q, g, k, v, o
    wcast_kernel<<<dim3(4, 4, 5), 256, 0, stream>>>(wq, wg, wk, wv, wo, wT);
    bpfrag_kernel<<<dim3(8, 8, 8), 256, 0, stream>>>(bias_pair, bpf);
    bmscale_kernel<<<dim3(32), 256, 0, stream>>>(bias_mask, bm2);

    proj_gemm_kernel<<<dim3(512), 256, 0, stream>>>(
        q_x, k_x, v_x, wT, bg, ws_q, ws_k, ws_vT, ws_g);

    attn_kernel<<<dim3(NSEQ, HEADS, QLEN / 128), 256, 0, stream>>>(
        ws_q, ws_k, ws_vT, ws_g, ws_o, bm2, bpf);

    outproj_kernel<<<dim3(512), 256, 0, stream>>>(
        ws_o, wT + 4 * 65536, bo, out);
}